// Round 1
// baseline (718.878 us; speedup 1.0000x reference)
//
#include <hip/hip_runtime.h>

#define N_NODES 100000
#define N_EDGES 1600000
#define IN_F 128
#define HID 64
#define OUT_F 32

// ---------------- degree / dinv ----------------

__global__ __launch_bounds__(256) void deg_kernel(const int* __restrict__ col,
                                                  float* __restrict__ deg) {
    int e = blockIdx.x * blockDim.x + threadIdx.x;
    if (e < N_EDGES) atomicAdd(&deg[col[e]], 1.0f);
}

__global__ __launch_bounds__(256) void dinv_kernel(float* __restrict__ dinv) {
    int n = blockIdx.x * blockDim.x + threadIdx.x;
    if (n < N_NODES) dinv[n] = rsqrtf(dinv[n] + 1.0f);  // +1 = self-loop
}

// ---------------- layer 1 dense: g1 = (x @ W1) * dinv ----------------
// block = 256 threads, 4 nodes per tile, W1 (128x64 = 32KB) in LDS.

__global__ __launch_bounds__(256) void gemm1_kernel(const float* __restrict__ x,
                                                    const float* __restrict__ W1,
                                                    const float* __restrict__ dinv,
                                                    float* __restrict__ g1) {
    __shared__ float w[IN_F * HID];   // 32 KB
    __shared__ float xs[4 * IN_F];    // 2 KB
    for (int i = threadIdx.x; i < IN_F * HID; i += 256) w[i] = W1[i];
    __syncthreads();

    int ntiles = (N_NODES + 3) / 4;
    for (int tile = blockIdx.x; tile < ntiles; tile += gridDim.x) {
        int base = tile * 4;
        for (int i = threadIdx.x; i < 4 * IN_F; i += 256) {
            int n = base + i / IN_F;
            xs[i] = (n < N_NODES) ? x[(size_t)n * IN_F + (i % IN_F)] : 0.0f;
        }
        __syncthreads();
        int nl = threadIdx.x >> 6;   // 0..3
        int f  = threadIdx.x & 63;   // 0..63
        int n  = base + nl;
        if (n < N_NODES) {
            float acc = 0.0f;
#pragma unroll
            for (int k = 0; k < IN_F; ++k)
                acc += xs[nl * IN_F + k] * w[k * HID + f];
            g1[(size_t)n * HID + f] = acc * dinv[n];
        }
        __syncthreads();
    }
}

// ---------------- layer 1 scatter: acc1[col] += g1[row] ----------------
// one wave (64 lanes) per edge; lane = feature. Coalesced gather + atomics.

__global__ __launch_bounds__(256) void scatter1_kernel(const int* __restrict__ row,
                                                       const int* __restrict__ col,
                                                       const float* __restrict__ g1,
                                                       float* __restrict__ acc1) {
    int wid  = (blockIdx.x * blockDim.x + threadIdx.x) >> 6;
    int lane = threadIdx.x & 63;
    int nw   = (gridDim.x * blockDim.x) >> 6;
    for (int e = wid; e < N_EDGES; e += nw) {
        int r = row[e], c = col[e];
        float v = g1[(size_t)r * HID + lane];
        atomicAdd(&acc1[(size_t)c * HID + lane], v);
    }
}

// ---------------- finalize1 + layer 2 dense ----------------
// out1 = relu(dinv*(acc1+g1)+b1) built in LDS (8 nodes/tile), then
// g2 = (out1 @ W2) * dinv.  W2 (64x32 = 8KB) in LDS.

__global__ __launch_bounds__(256) void fin1_gemm2_kernel(const float* __restrict__ acc1,
                                                         const float* __restrict__ g1,
                                                         const float* __restrict__ dinv,
                                                         const float* __restrict__ b1,
                                                         const float* __restrict__ W2,
                                                         float* __restrict__ g2) {
    __shared__ float w[HID * OUT_F];  // 8 KB
    __shared__ float hs[8 * HID];     // 2 KB
    for (int i = threadIdx.x; i < HID * OUT_F; i += 256) w[i] = W2[i];
    __syncthreads();

    int ntiles = (N_NODES + 7) / 8;
    for (int tile = blockIdx.x; tile < ntiles; tile += gridDim.x) {
        int base = tile * 8;
#pragma unroll
        for (int v = 0; v < 2; ++v) {
            int i  = threadIdx.x + v * 256;
            int nl = i >> 6, f = i & 63;
            int n  = base + nl;
            if (n < N_NODES) {
                float t = dinv[n] * (acc1[(size_t)n * HID + f] + g1[(size_t)n * HID + f]) + b1[f];
                hs[i] = t > 0.0f ? t : 0.0f;
            }
        }
        __syncthreads();
        int nl = threadIdx.x >> 5;   // 0..7
        int f  = threadIdx.x & 31;   // 0..31
        int n  = base + nl;
        if (n < N_NODES) {
            float acc = 0.0f;
#pragma unroll
            for (int k = 0; k < HID; ++k)
                acc += hs[nl * HID + k] * w[k * OUT_F + f];
            g2[(size_t)n * OUT_F + f] = acc * dinv[n];
        }
        __syncthreads();
    }
}

// ---------------- layer 2 scatter: out[col] += g2[row] ----------------
// half-wave (32 lanes) per edge.

__global__ __launch_bounds__(256) void scatter2_kernel(const int* __restrict__ row,
                                                       const int* __restrict__ col,
                                                       const float* __restrict__ g2,
                                                       float* __restrict__ out) {
    int idx = blockIdx.x * blockDim.x + threadIdx.x;
    int e = idx >> 5;
    int f = idx & 31;
    if (e < N_EDGES) {
        int r = row[e], c = col[e];
        atomicAdd(&out[(size_t)c * OUT_F + f], g2[(size_t)r * OUT_F + f]);
    }
}

// ---------------- finalize2: out = dinv*(out+g2_self)+b2 ----------------

__global__ __launch_bounds__(256) void fin2_kernel(const float* __restrict__ g2,
                                                   const float* __restrict__ dinv,
                                                   const float* __restrict__ b2,
                                                   float* __restrict__ out) {
    int i = blockIdx.x * blockDim.x + threadIdx.x;
    if (i < N_NODES * OUT_F) {
        int n = i >> 5, f = i & 31;
        out[i] = dinv[n] * (out[i] + g2[i]) + b2[f];
    }
}

extern "C" void kernel_launch(void* const* d_in, const int* in_sizes, int n_in,
                              void* d_out, int out_size, void* d_ws, size_t ws_size,
                              hipStream_t stream) {
    const float* x   = (const float*)d_in[0];
    const int*   ei  = (const int*)d_in[1];
    const int*   row = ei;             // edge_index[0] = source
    const int*   col = ei + N_EDGES;   // edge_index[1] = target
    const float* W1  = (const float*)d_in[2];
    const float* b1  = (const float*)d_in[3];
    const float* W2  = (const float*)d_in[4];
    const float* b2  = (const float*)d_in[5];
    float* out = (float*)d_out;

    float* ws   = (float*)d_ws;
    float* dinv = ws;                                   // N
    float* g1   = dinv + N_NODES;                       // N*64
    float* acc1 = g1 + (size_t)N_NODES * HID;           // N*64
    float* g2   = acc1 + (size_t)N_NODES * HID;         // N*32
    // total: N*(1+64+64+32)*4B = 64.4 MB

    hipMemsetAsync(dinv, 0, (size_t)N_NODES * sizeof(float), stream);
    hipMemsetAsync(acc1, 0, (size_t)N_NODES * HID * sizeof(float), stream);
    hipMemsetAsync(out,  0, (size_t)N_NODES * OUT_F * sizeof(float), stream);

    deg_kernel<<<(N_EDGES + 255) / 256, 256, 0, stream>>>(col, dinv);
    dinv_kernel<<<(N_NODES + 255) / 256, 256, 0, stream>>>(dinv);
    gemm1_kernel<<<2048, 256, 0, stream>>>(x, W1, dinv, g1);
    scatter1_kernel<<<N_EDGES / 4, 256, 0, stream>>>(row, col, g1, acc1);
    fin1_gemm2_kernel<<<2048, 256, 0, stream>>>(acc1, g1, dinv, b1, W2, g2);
    scatter2_kernel<<<(N_EDGES * 32) / 256, 256, 0, stream>>>(row, col, g2, out);
    fin2_kernel<<<(N_NODES * OUT_F + 255) / 256, 256, 0, stream>>>(g2, dinv, b2, out);
}

// Round 2
// 420.733 us; speedup vs baseline: 1.7086x; 1.7086x over previous
//
#include <hip/hip_runtime.h>

#define N_NODES 100000
#define N_EDGES 1600000
#define IN_F 128
#define HID 64
#define OUT_F 32
#define NB_SCAN ((N_NODES + 255) / 256)  // 391

// ---------------- degree histogram (int) ----------------

__global__ __launch_bounds__(256) void hist_kernel(const int* __restrict__ col,
                                                   int* __restrict__ deg) {
    int e = blockIdx.x * 256 + threadIdx.x;
    if (e < N_EDGES) atomicAdd(&deg[col[e]], 1);
}

__global__ __launch_bounds__(256) void dinv_kernel(const int* __restrict__ deg,
                                                   float* __restrict__ dinv) {
    int n = blockIdx.x * 256 + threadIdx.x;
    if (n < N_NODES) dinv[n] = rsqrtf((float)deg[n] + 1.0f);  // +1 = self-loop
}

// ---------------- exclusive scan of deg -> rowptr (3 phases) ----------------

__global__ __launch_bounds__(256) void scan1_kernel(const int* __restrict__ deg,
                                                    int* __restrict__ excl,
                                                    int* __restrict__ bsum) {
    __shared__ int s[256];
    int t = threadIdx.x, i = blockIdx.x * 256 + t;
    int v = (i < N_NODES) ? deg[i] : 0;
    s[t] = v; __syncthreads();
    for (int off = 1; off < 256; off <<= 1) {
        int x = (t >= off) ? s[t - off] : 0; __syncthreads();
        s[t] += x; __syncthreads();
    }
    if (i < N_NODES) excl[i] = s[t] - v;
    if (t == 255) bsum[blockIdx.x] = s[255];
}

__global__ __launch_bounds__(512) void scan2_kernel(int* __restrict__ bsum) {
    __shared__ int s[512];
    int t = threadIdx.x;
    int v = (t < NB_SCAN) ? bsum[t] : 0;
    s[t] = v; __syncthreads();
    for (int off = 1; off < 512; off <<= 1) {
        int x = (t >= off) ? s[t - off] : 0; __syncthreads();
        s[t] += x; __syncthreads();
    }
    if (t < NB_SCAN) bsum[t] = s[t] - v;  // exclusive block offsets
}

__global__ __launch_bounds__(256) void scan3_kernel(int* __restrict__ excl,
                                                    const int* __restrict__ bsum,
                                                    int* __restrict__ cursor) {
    int i = blockIdx.x * 256 + threadIdx.x;
    if (i < N_NODES) {
        int rp = excl[i] + bsum[blockIdx.x];
        excl[i] = rp;      // excl now holds rowptr
        cursor[i] = rp;
    }
}

// ---------------- reorder: srt[pos] = row, bucketed by col ----------------

__global__ __launch_bounds__(256) void reorder_kernel(const int* __restrict__ row,
                                                      const int* __restrict__ col,
                                                      int* __restrict__ cursor,
                                                      int* __restrict__ srt) {
    int e = blockIdx.x * 256 + threadIdx.x;
    if (e < N_EDGES) {
        int pos = atomicAdd(&cursor[col[e]], 1);
        srt[pos] = row[e];
    }
}

// ---------------- layer 1 dense: g1 = (x @ W1) * dinv ----------------

__global__ __launch_bounds__(256) void gemm1_kernel(const float* __restrict__ x,
                                                    const float* __restrict__ W1,
                                                    const float* __restrict__ dinv,
                                                    float* __restrict__ g1) {
    __shared__ float w[IN_F * HID];   // 32 KB
    __shared__ float xs[4 * IN_F];    // 2 KB
    for (int i = threadIdx.x; i < IN_F * HID; i += 256) w[i] = W1[i];
    __syncthreads();

    int ntiles = (N_NODES + 3) / 4;
    for (int tile = blockIdx.x; tile < ntiles; tile += gridDim.x) {
        int base = tile * 4;
        for (int i = threadIdx.x; i < 4 * IN_F; i += 256) {
            int n = base + i / IN_F;
            xs[i] = (n < N_NODES) ? x[(size_t)n * IN_F + (i % IN_F)] : 0.0f;
        }
        __syncthreads();
        int nl = threadIdx.x >> 6;
        int f  = threadIdx.x & 63;
        int n  = base + nl;
        if (n < N_NODES) {
            float acc = 0.0f;
#pragma unroll
            for (int k = 0; k < IN_F; ++k)
                acc += xs[nl * IN_F + k] * w[k * HID + f];
            g1[(size_t)n * HID + f] = acc * dinv[n];
        }
        __syncthreads();
    }
}

// ---------------- layer 1 gather + finalize1: h = relu(dinv*(sum+self)+b1) ----
// one 64-lane wave per node, lane = feature, 4-edge unroll for MLP.

__global__ __launch_bounds__(256) void gather1_kernel(const int* __restrict__ rowptr,
                                                      const int* __restrict__ deg,
                                                      const int* __restrict__ srt,
                                                      const float* __restrict__ g1,
                                                      const float* __restrict__ dinv,
                                                      const float* __restrict__ b1,
                                                      float* __restrict__ h) {
    int n = blockIdx.x * 4 + (threadIdx.x >> 6);
    int lane = threadIdx.x & 63;
    if (n >= N_NODES) return;
    int s = rowptr[n], e = s + deg[n];
    float a0 = 0.f, a1 = 0.f, a2 = 0.f, a3 = 0.f;
    int j = s;
    for (; j + 4 <= e; j += 4) {
        int r0 = srt[j], r1 = srt[j + 1], r2 = srt[j + 2], r3 = srt[j + 3];
        a0 += g1[(size_t)r0 * HID + lane];
        a1 += g1[(size_t)r1 * HID + lane];
        a2 += g1[(size_t)r2 * HID + lane];
        a3 += g1[(size_t)r3 * HID + lane];
    }
    for (; j < e; ++j) a0 += g1[(size_t)srt[j] * HID + lane];
    float sum = (a0 + a1) + (a2 + a3) + g1[(size_t)n * HID + lane];  // + self-loop
    float t = dinv[n] * sum + b1[lane];
    h[(size_t)n * HID + lane] = t > 0.f ? t : 0.f;
}

// ---------------- layer 2 dense: g2 = (h @ W2) * dinv ----------------

__global__ __launch_bounds__(256) void gemm2_kernel(const float* __restrict__ h,
                                                    const float* __restrict__ dinv,
                                                    const float* __restrict__ W2,
                                                    float* __restrict__ g2) {
    __shared__ float w[HID * OUT_F];  // 8 KB
    __shared__ float hs[8 * HID];     // 2 KB
    for (int i = threadIdx.x; i < HID * OUT_F; i += 256) w[i] = W2[i];
    __syncthreads();

    int ntiles = (N_NODES + 7) / 8;
    for (int tile = blockIdx.x; tile < ntiles; tile += gridDim.x) {
        int base = tile * 8;
#pragma unroll
        for (int v = 0; v < 2; ++v) {
            int i  = threadIdx.x + v * 256;
            int nl = i >> 6, f = i & 63;
            int n  = base + nl;
            if (n < N_NODES) hs[i] = h[(size_t)n * HID + f];
        }
        __syncthreads();
        int nl = threadIdx.x >> 5;
        int f  = threadIdx.x & 31;
        int n  = base + nl;
        if (n < N_NODES) {
            float acc = 0.0f;
#pragma unroll
            for (int k = 0; k < HID; ++k)
                acc += hs[nl * HID + k] * w[k * OUT_F + f];
            g2[(size_t)n * OUT_F + f] = acc * dinv[n];
        }
        __syncthreads();
    }
}

// ---------------- layer 2 gather + finalize2 ----------------
// half-wave (32 lanes) per node, lane = feature.

__global__ __launch_bounds__(256) void gather2_kernel(const int* __restrict__ rowptr,
                                                      const int* __restrict__ deg,
                                                      const int* __restrict__ srt,
                                                      const float* __restrict__ g2,
                                                      const float* __restrict__ dinv,
                                                      const float* __restrict__ b2,
                                                      float* __restrict__ out) {
    int n = blockIdx.x * 8 + (threadIdx.x >> 5);
    int f = threadIdx.x & 31;
    if (n >= N_NODES) return;
    int s = rowptr[n], e = s + deg[n];
    float a0 = 0.f, a1 = 0.f, a2 = 0.f, a3 = 0.f;
    int j = s;
    for (; j + 4 <= e; j += 4) {
        int r0 = srt[j], r1 = srt[j + 1], r2 = srt[j + 2], r3 = srt[j + 3];
        a0 += g2[(size_t)r0 * OUT_F + f];
        a1 += g2[(size_t)r1 * OUT_F + f];
        a2 += g2[(size_t)r2 * OUT_F + f];
        a3 += g2[(size_t)r3 * OUT_F + f];
    }
    for (; j < e; ++j) a0 += g2[(size_t)srt[j] * OUT_F + f];
    float sum = (a0 + a1) + (a2 + a3) + g2[(size_t)n * OUT_F + f];  // + self-loop
    out[(size_t)n * OUT_F + f] = dinv[n] * sum + b2[f];
}

extern "C" void kernel_launch(void* const* d_in, const int* in_sizes, int n_in,
                              void* d_out, int out_size, void* d_ws, size_t ws_size,
                              hipStream_t stream) {
    const float* x   = (const float*)d_in[0];
    const int*   ei  = (const int*)d_in[1];
    const int*   row = ei;             // edge_index[0] = source
    const int*   col = ei + N_EDGES;   // edge_index[1] = target
    const float* W1  = (const float*)d_in[2];
    const float* b1  = (const float*)d_in[3];
    const float* W2  = (const float*)d_in[4];
    const float* b2  = (const float*)d_in[5];
    float* out = (float*)d_out;

    // workspace layout
    char* p = (char*)d_ws;
    float* dinv  = (float*)p; p += (size_t)N_NODES * 4;          // 0.4 MB
    float* g1    = (float*)p; p += (size_t)N_NODES * HID * 4;    // 25.6 MB
    float* h     = (float*)p; p += (size_t)N_NODES * HID * 4;    // 25.6 MB
    float* g2    = (float*)p; p += (size_t)N_NODES * OUT_F * 4;  // 12.8 MB
    int*   deg   = (int*)p;   p += (size_t)N_NODES * 4;          // 0.4 MB
    int*   rowp  = (int*)p;   p += (size_t)(N_NODES + 1) * 4;    // 0.4 MB (excl->rowptr)
    int*   curs  = (int*)p;   p += (size_t)N_NODES * 4;          // 0.4 MB
    int*   bsum  = (int*)p;   p += 512 * 4;
    int*   srt   = (int*)p;   p += (size_t)N_EDGES * 4;          // 6.4 MB
    // total ~72.1 MB

    hipMemsetAsync(deg, 0, (size_t)N_NODES * sizeof(int), stream);

    hist_kernel  <<<(N_EDGES + 255) / 256, 256, 0, stream>>>(col, deg);
    dinv_kernel  <<<NB_SCAN, 256, 0, stream>>>(deg, dinv);
    scan1_kernel <<<NB_SCAN, 256, 0, stream>>>(deg, rowp, bsum);
    scan2_kernel <<<1, 512, 0, stream>>>(bsum);
    scan3_kernel <<<NB_SCAN, 256, 0, stream>>>(rowp, bsum, curs);
    reorder_kernel<<<(N_EDGES + 255) / 256, 256, 0, stream>>>(row, col, curs, srt);

    gemm1_kernel <<<2048, 256, 0, stream>>>(x, W1, dinv, g1);
    gather1_kernel<<<(N_NODES + 3) / 4, 256, 0, stream>>>(rowp, deg, srt, g1, dinv, b1, h);
    gemm2_kernel <<<2048, 256, 0, stream>>>(h, dinv, W2, g2);
    gather2_kernel<<<(N_NODES + 7) / 8, 256, 0, stream>>>(rowp, deg, srt, g2, dinv, b2, out);
}

// Round 6
// 355.965 us; speedup vs baseline: 2.0195x; 1.1820x over previous
//
#include <hip/hip_runtime.h>

#define N_NODES 100000
#define N_EDGES 1600000
#define IN_F 128
#define HID 64
#define OUT_F 32
#define NB_SCAN ((N_NODES + 255) / 256)  // 391

#define BSHIFT 10
#define BUCK_N (1 << BSHIFT)                               // 1024 nodes/bucket
#define NBUCK ((N_NODES + BUCK_N - 1) >> BSHIFT)           // 98
#define EPB 8192
#define NBLK_A ((N_EDGES + EPB - 1) / EPB)                 // 196

// ---------------- degree histogram (int) ----------------

__global__ __launch_bounds__(256) void hist_kernel(const int* __restrict__ col,
                                                   int* __restrict__ deg) {
    int e = blockIdx.x * 256 + threadIdx.x;
    if (e < N_EDGES) atomicAdd(&deg[col[e]], 1);
}

__global__ __launch_bounds__(256) void dinv_kernel(const int* __restrict__ deg,
                                                   float* __restrict__ dinv) {
    int n = blockIdx.x * 256 + threadIdx.x;
    if (n < N_NODES) dinv[n] = rsqrtf((float)deg[n] + 1.0f);  // +1 = self-loop
}

// ---------------- exclusive scan of deg -> rowptr (3 phases) ----------------

__global__ __launch_bounds__(256) void scan1_kernel(const int* __restrict__ deg,
                                                    int* __restrict__ excl,
                                                    int* __restrict__ bsum) {
    __shared__ int s[256];
    int t = threadIdx.x, i = blockIdx.x * 256 + t;
    int v = (i < N_NODES) ? deg[i] : 0;
    s[t] = v; __syncthreads();
    for (int off = 1; off < 256; off <<= 1) {
        int x = (t >= off) ? s[t - off] : 0; __syncthreads();
        s[t] += x; __syncthreads();
    }
    if (i < N_NODES) excl[i] = s[t] - v;
    if (t == 255) bsum[blockIdx.x] = s[255];
}

__global__ __launch_bounds__(512) void scan2_kernel(int* __restrict__ bsum) {
    __shared__ int s[512];
    int t = threadIdx.x;
    int v = (t < NB_SCAN) ? bsum[t] : 0;
    s[t] = v; __syncthreads();
    for (int off = 1; off < 512; off <<= 1) {
        int x = (t >= off) ? s[t - off] : 0; __syncthreads();
        s[t] += x; __syncthreads();
    }
    if (t < NB_SCAN) bsum[t] = s[t] - v;  // exclusive block offsets
}

__global__ __launch_bounds__(256) void scan3_kernel(int* __restrict__ excl,
                                                    const int* __restrict__ bsum) {
    int i = blockIdx.x * 256 + threadIdx.x;
    if (i < N_NODES) excl[i] += bsum[blockIdx.x];  // excl now holds rowptr
}

// ---------------- binned reorder ----------------
// binit: bucket global cursors start at rowp[bucket_base_node]

__global__ void binit_kernel(const int* __restrict__ rowp, int* __restrict__ gcur) {
    int b = blockIdx.x * 64 + threadIdx.x;
    if (b < NBUCK) gcur[b] = rowp[b << BSHIFT];
}

// pass A: group edges by bucket into tmp (int2 = row,col), bucket-contiguous.

__global__ __launch_bounds__(256) void binA_kernel(const int* __restrict__ row,
                                                   const int* __restrict__ col,
                                                   int* __restrict__ gcur,
                                                   int2* __restrict__ tmp) {
    __shared__ int cnt[NBUCK], base[NBUCK], lcur[NBUCK];
    int t = threadIdx.x;
    int e0 = blockIdx.x * EPB;
    int e1 = e0 + EPB < N_EDGES ? e0 + EPB : N_EDGES;
    for (int i = t; i < NBUCK; i += 256) cnt[i] = 0;
    __syncthreads();
    for (int e = e0 + t; e < e1; e += 256) atomicAdd(&cnt[col[e] >> BSHIFT], 1);
    __syncthreads();
    for (int i = t; i < NBUCK; i += 256) {
        int c = cnt[i];
        base[i] = c ? atomicAdd(&gcur[i], c) : 0;
        lcur[i] = 0;
    }
    __syncthreads();
    for (int e = e0 + t; e < e1; e += 256) {
        int c = col[e];
        int b = c >> BSHIFT;
        int rk = atomicAdd(&lcur[b], 1);
        tmp[base[b] + rk] = make_int2(row[e], c);
    }
}

// pass B: within a bucket, counting-sort into srt via LDS cursors.
// scatter range per block ~65 KB -> cache-resident.

__global__ __launch_bounds__(512) void binB_kernel(const int* __restrict__ rowp,
                                                   const int2* __restrict__ tmp,
                                                   int* __restrict__ srt) {
    __shared__ int curs[BUCK_N];  // 4 KB
    int b = blockIdx.x, t = threadIdx.x;
    int nbase = b << BSHIFT;
    int nend = nbase + BUCK_N < N_NODES ? nbase + BUCK_N : N_NODES;
    for (int i = t; i < nend - nbase; i += 512) curs[i] = rowp[nbase + i];
    __syncthreads();
    int s  = rowp[nbase];
    int e1 = (nend < N_NODES) ? rowp[nend] : N_EDGES;
    for (int e = s + t; e < e1; e += 512) {
        int2 rc = tmp[e];
        int pos = atomicAdd(&curs[rc.y - nbase], 1);
        srt[pos] = rc.x;
    }
}

// ---------------- layer 1 dense: g1 = (x @ W1) * dinv ----------------

__global__ __launch_bounds__(256) void gemm1_kernel(const float* __restrict__ x,
                                                    const float* __restrict__ W1,
                                                    const float* __restrict__ dinv,
                                                    float* __restrict__ g1) {
    __shared__ float w[IN_F * HID];   // 32 KB
    __shared__ float xs[4 * IN_F];    // 2 KB
    for (int i = threadIdx.x; i < IN_F * HID; i += 256) w[i] = W1[i];
    __syncthreads();

    int ntiles = (N_NODES + 3) / 4;
    for (int tile = blockIdx.x; tile < ntiles; tile += gridDim.x) {
        int base = tile * 4;
        for (int i = threadIdx.x; i < 4 * IN_F; i += 256) {
            int n = base + i / IN_F;
            xs[i] = (n < N_NODES) ? x[(size_t)n * IN_F + (i % IN_F)] : 0.0f;
        }
        __syncthreads();
        int nl = threadIdx.x >> 6;
        int f  = threadIdx.x & 63;
        int n  = base + nl;
        if (n < N_NODES) {
            float acc = 0.0f;
#pragma unroll
            for (int k = 0; k < IN_F; ++k)
                acc += xs[nl * IN_F + k] * w[k * HID + f];
            g1[(size_t)n * HID + f] = acc * dinv[n];
        }
        __syncthreads();
    }
}

// ---------------- layer 1 gather + finalize1 ----------------
// one 64-lane wave per node, lane = feature, 8-edge unroll for MLP.

__global__ __launch_bounds__(256) void gather1_kernel(const int* __restrict__ rowptr,
                                                      const int* __restrict__ deg,
                                                      const int* __restrict__ srt,
                                                      const float* __restrict__ g1,
                                                      const float* __restrict__ dinv,
                                                      const float* __restrict__ b1,
                                                      float* __restrict__ h) {
    int n = blockIdx.x * 4 + (threadIdx.x >> 6);
    int lane = threadIdx.x & 63;
    if (n >= N_NODES) return;
    int s = rowptr[n], e = s + deg[n];
    float a0 = 0.f, a1 = 0.f, a2 = 0.f, a3 = 0.f;
    float a4 = 0.f, a5 = 0.f, a6 = 0.f, a7 = 0.f;
    int j = s;
    for (; j + 8 <= e; j += 8) {
        int r0 = srt[j],     r1 = srt[j + 1], r2 = srt[j + 2], r3 = srt[j + 3];
        int r4 = srt[j + 4], r5 = srt[j + 5], r6 = srt[j + 6], r7 = srt[j + 7];
        a0 += g1[(size_t)r0 * HID + lane];
        a1 += g1[(size_t)r1 * HID + lane];
        a2 += g1[(size_t)r2 * HID + lane];
        a3 += g1[(size_t)r3 * HID + lane];
        a4 += g1[(size_t)r4 * HID + lane];
        a5 += g1[(size_t)r5 * HID + lane];
        a6 += g1[(size_t)r6 * HID + lane];
        a7 += g1[(size_t)r7 * HID + lane];
    }
    for (; j < e; ++j) a0 += g1[(size_t)srt[j] * HID + lane];
    float sum = ((a0 + a1) + (a2 + a3)) + ((a4 + a5) + (a6 + a7))
              + g1[(size_t)n * HID + lane];  // + self-loop
    float t = dinv[n] * sum + b1[lane];
    h[(size_t)n * HID + lane] = t > 0.f ? t : 0.f;
}

// ---------------- layer 2 dense: g2 = (h @ W2) * dinv ----------------

__global__ __launch_bounds__(256) void gemm2_kernel(const float* __restrict__ h,
                                                    const float* __restrict__ dinv,
                                                    const float* __restrict__ W2,
                                                    float* __restrict__ g2) {
    __shared__ float w[HID * OUT_F];  // 8 KB
    __shared__ float hs[8 * HID];     // 2 KB
    for (int i = threadIdx.x; i < HID * OUT_F; i += 256) w[i] = W2[i];
    __syncthreads();

    int ntiles = (N_NODES + 7) / 8;
    for (int tile = blockIdx.x; tile < ntiles; tile += gridDim.x) {
        int base = tile * 8;
#pragma unroll
        for (int v = 0; v < 2; ++v) {
            int i  = threadIdx.x + v * 256;
            int nl = i >> 6, f = i & 63;
            int n  = base + nl;
            if (n < N_NODES) hs[i] = h[(size_t)n * HID + f];
        }
        __syncthreads();
        int nl = threadIdx.x >> 5;
        int f  = threadIdx.x & 31;
        int n  = base + nl;
        if (n < N_NODES) {
            float acc = 0.0f;
#pragma unroll
            for (int k = 0; k < HID; ++k)
                acc += hs[nl * HID + k] * w[k * OUT_F + f];
            g2[(size_t)n * OUT_F + f] = acc * dinv[n];
        }
        __syncthreads();
    }
}

// ---------------- layer 2 gather + finalize2 ----------------
// half-wave (32 lanes) per node, 8-edge unroll.

__global__ __launch_bounds__(256) void gather2_kernel(const int* __restrict__ rowptr,
                                                      const int* __restrict__ deg,
                                                      const int* __restrict__ srt,
                                                      const float* __restrict__ g2,
                                                      const float* __restrict__ dinv,
                                                      const float* __restrict__ b2,
                                                      float* __restrict__ out) {
    int n = blockIdx.x * 8 + (threadIdx.x >> 5);
    int f = threadIdx.x & 31;
    if (n >= N_NODES) return;
    int s = rowptr[n], e = s + deg[n];
    float a0 = 0.f, a1 = 0.f, a2 = 0.f, a3 = 0.f;
    float a4 = 0.f, a5 = 0.f, a6 = 0.f, a7 = 0.f;
    int j = s;
    for (; j + 8 <= e; j += 8) {
        int r0 = srt[j],     r1 = srt[j + 1], r2 = srt[j + 2], r3 = srt[j + 3];
        int r4 = srt[j + 4], r5 = srt[j + 5], r6 = srt[j + 6], r7 = srt[j + 7];
        a0 += g2[(size_t)r0 * OUT_F + f];
        a1 += g2[(size_t)r1 * OUT_F + f];
        a2 += g2[(size_t)r2 * OUT_F + f];
        a3 += g2[(size_t)r3 * OUT_F + f];
        a4 += g2[(size_t)r4 * OUT_F + f];
        a5 += g2[(size_t)r5 * OUT_F + f];
        a6 += g2[(size_t)r6 * OUT_F + f];
        a7 += g2[(size_t)r7 * OUT_F + f];
    }
    for (; j < e; ++j) a0 += g2[(size_t)srt[j] * OUT_F + f];
    float sum = ((a0 + a1) + (a2 + a3)) + ((a4 + a5) + (a6 + a7))
              + g2[(size_t)n * OUT_F + f];  // + self-loop
    out[(size_t)n * OUT_F + f] = dinv[n] * sum + b2[f];
}

extern "C" void kernel_launch(void* const* d_in, const int* in_sizes, int n_in,
                              void* d_out, int out_size, void* d_ws, size_t ws_size,
                              hipStream_t stream) {
    const float* x   = (const float*)d_in[0];
    const int*   ei  = (const int*)d_in[1];
    const int*   row = ei;             // edge_index[0] = source
    const int*   col = ei + N_EDGES;   // edge_index[1] = target
    const float* W1  = (const float*)d_in[2];
    const float* b1  = (const float*)d_in[3];
    const float* W2  = (const float*)d_in[4];
    const float* b2  = (const float*)d_in[5];
    float* out = (float*)d_out;

    // workspace layout
    char* p = (char*)d_ws;
    float* dinv  = (float*)p; p += (size_t)N_NODES * 4;          // 0.4 MB
    float* g1    = (float*)p; p += (size_t)N_NODES * HID * 4;    // 25.6 MB
    float* h     = (float*)p; p += (size_t)N_NODES * HID * 4;    // 25.6 MB
    float* g2    = (float*)p; p += (size_t)N_NODES * OUT_F * 4;  // 12.8 MB
    int*   deg   = (int*)p;   p += (size_t)N_NODES * 4;          // 0.4 MB
    int*   rowp  = (int*)p;   p += (size_t)(N_NODES + 1) * 4;    // 0.4 MB
    int*   bsum  = (int*)p;   p += 512 * 4;
    int*   gcur  = (int*)p;   p += ((NBUCK + 63) & ~63) * 4;
    int*   srt   = (int*)p;   p += (size_t)N_EDGES * 4;          // 6.4 MB
    int2*  tmp   = (int2*)h;  // alias: tmp (12.8 MB) dead before gather1 writes h

    hipMemsetAsync(deg, 0, (size_t)N_NODES * sizeof(int), stream);

    hist_kernel  <<<(N_EDGES + 255) / 256, 256, 0, stream>>>(col, deg);
    dinv_kernel  <<<NB_SCAN, 256, 0, stream>>>(deg, dinv);
    scan1_kernel <<<NB_SCAN, 256, 0, stream>>>(deg, rowp, bsum);
    scan2_kernel <<<1, 512, 0, stream>>>(bsum);
    scan3_kernel <<<NB_SCAN, 256, 0, stream>>>(rowp, bsum);
    binit_kernel <<<(NBUCK + 63) / 64, 64, 0, stream>>>(rowp, gcur);
    binA_kernel  <<<NBLK_A, 256, 0, stream>>>(row, col, gcur, tmp);
    binB_kernel  <<<NBUCK, 512, 0, stream>>>(rowp, tmp, srt);

    gemm1_kernel <<<2048, 256, 0, stream>>>(x, W1, dinv, g1);
    gather1_kernel<<<(N_NODES + 3) / 4, 256, 0, stream>>>(rowp, deg, srt, g1, dinv, b1, h);
    gemm2_kernel <<<2048, 256, 0, stream>>>(h, dinv, W2, g2);
    gather2_kernel<<<(N_NODES + 7) / 8, 256, 0, stream>>>(rowp, deg, srt, g2, dinv, b2, out);
}

// Round 7
// 331.851 us; speedup vs baseline: 2.1663x; 1.0727x over previous
//
#include <hip/hip_runtime.h>

#define N_NODES 100000
#define N_EDGES 1600000
#define IN_F 128
#define HID 64
#define OUT_F 32
#define NB_SCAN ((N_NODES + 255) / 256)  // 391

#define BSHIFT 10
#define BUCK_N (1 << BSHIFT)                               // 1024 nodes/bucket
#define NBUCK ((N_NODES + BUCK_N - 1) >> BSHIFT)           // 98
#define EPB 8192
#define NBLK_A ((N_EDGES + EPB - 1) / EPB)                 // 196

// ---------------- degree histogram (int) ----------------

__global__ __launch_bounds__(256) void hist_kernel(const int* __restrict__ col,
                                                   int* __restrict__ deg) {
    int e = blockIdx.x * 256 + threadIdx.x;
    if (e < N_EDGES) atomicAdd(&deg[col[e]], 1);
}

__global__ __launch_bounds__(256) void dinv_kernel(const int* __restrict__ deg,
                                                   float* __restrict__ dinv) {
    int n = blockIdx.x * 256 + threadIdx.x;
    if (n < N_NODES) dinv[n] = rsqrtf((float)deg[n] + 1.0f);  // +1 = self-loop
}

// ---------------- exclusive scan of deg -> rowptr (3 phases) ----------------

__global__ __launch_bounds__(256) void scan1_kernel(const int* __restrict__ deg,
                                                    int* __restrict__ excl,
                                                    int* __restrict__ bsum) {
    __shared__ int s[256];
    int t = threadIdx.x, i = blockIdx.x * 256 + t;
    int v = (i < N_NODES) ? deg[i] : 0;
    s[t] = v; __syncthreads();
    for (int off = 1; off < 256; off <<= 1) {
        int x = (t >= off) ? s[t - off] : 0; __syncthreads();
        s[t] += x; __syncthreads();
    }
    if (i < N_NODES) excl[i] = s[t] - v;
    if (t == 255) bsum[blockIdx.x] = s[255];
}

__global__ __launch_bounds__(512) void scan2_kernel(int* __restrict__ bsum) {
    __shared__ int s[512];
    int t = threadIdx.x;
    int v = (t < NB_SCAN) ? bsum[t] : 0;
    s[t] = v; __syncthreads();
    for (int off = 1; off < 512; off <<= 1) {
        int x = (t >= off) ? s[t - off] : 0; __syncthreads();
        s[t] += x; __syncthreads();
    }
    if (t < NB_SCAN) bsum[t] = s[t] - v;  // exclusive block offsets
}

__global__ __launch_bounds__(256) void scan3_kernel(int* __restrict__ excl,
                                                    const int* __restrict__ bsum) {
    int i = blockIdx.x * 256 + threadIdx.x;
    if (i < N_NODES) excl[i] += bsum[blockIdx.x];  // excl now holds rowptr
}

// ---------------- binned reorder ----------------

__global__ void binit_kernel(const int* __restrict__ rowp, int* __restrict__ gcur) {
    int b = blockIdx.x * 64 + threadIdx.x;
    if (b < NBUCK) gcur[b] = rowp[b << BSHIFT];
}

// pass A: group edges by bucket into tmp (int2 = row,col), bucket-contiguous.

__global__ __launch_bounds__(256) void binA_kernel(const int* __restrict__ row,
                                                   const int* __restrict__ col,
                                                   int* __restrict__ gcur,
                                                   int2* __restrict__ tmp) {
    __shared__ int cnt[NBUCK], base[NBUCK], lcur[NBUCK];
    int t = threadIdx.x;
    int e0 = blockIdx.x * EPB;
    int e1 = e0 + EPB < N_EDGES ? e0 + EPB : N_EDGES;
    for (int i = t; i < NBUCK; i += 256) cnt[i] = 0;
    __syncthreads();
    for (int e = e0 + t; e < e1; e += 256) atomicAdd(&cnt[col[e] >> BSHIFT], 1);
    __syncthreads();
    for (int i = t; i < NBUCK; i += 256) {
        int c = cnt[i];
        base[i] = c ? atomicAdd(&gcur[i], c) : 0;
        lcur[i] = 0;
    }
    __syncthreads();
    for (int e = e0 + t; e < e1; e += 256) {
        int c = col[e];
        int b = c >> BSHIFT;
        int rk = atomicAdd(&lcur[b], 1);
        tmp[base[b] + rk] = make_int2(row[e], c);
    }
}

// pass B: within a bucket, counting-sort into srt via LDS cursors.

__global__ __launch_bounds__(512) void binB_kernel(const int* __restrict__ rowp,
                                                   const int2* __restrict__ tmp,
                                                   int* __restrict__ srt) {
    __shared__ int curs[BUCK_N];  // 4 KB
    int b = blockIdx.x, t = threadIdx.x;
    int nbase = b << BSHIFT;
    int nend = nbase + BUCK_N < N_NODES ? nbase + BUCK_N : N_NODES;
    for (int i = t; i < nend - nbase; i += 512) curs[i] = rowp[nbase + i];
    __syncthreads();
    int s  = rowp[nbase];
    int e1 = (nend < N_NODES) ? rowp[nend] : N_EDGES;
    for (int e = s + t; e < e1; e += 512) {
        int2 rc = tmp[e];
        int pos = atomicAdd(&curs[rc.y - nbase], 1);
        srt[pos] = rc.x;
    }
}

// ---------------- layer 1 dense: g1 = (x @ W1) * dinv ----------------
// register-tiled: tile 64 nodes x 64 f; thread = 4 nodes (stride 16) x 4 f.
// xs XOR-swizzled (float4 column-block ^ (row&7)) -> 2-way LDS reads (free).

__global__ __launch_bounds__(256) void gemm1_tiled(const float* __restrict__ x,
                                                   const float* __restrict__ W1,
                                                   const float* __restrict__ dinv,
                                                   float* __restrict__ g1) {
    __shared__ float w[IN_F * HID];       // 32 KB, [k][f] row-major (= W1 layout)
    __shared__ float xs[64 * IN_F];       // 32 KB, swizzled
    float4* xs4 = (float4*)xs;            // row stride 32 float4

    int t = threadIdx.x;
    int base = blockIdx.x * 64;

    for (int i = t; i < IN_F * HID; i += 256) w[i] = W1[i];

#pragma unroll
    for (int j = 0; j < 8; ++j) {         // 64 rows x 128 k = 8192 floats
        int idx = j * 1024 + t * 4;
        int n = idx >> 7;                 // 0..63
        int k = idx & 127;
        float4 v = make_float4(0.f, 0.f, 0.f, 0.f);
        if (base + n < N_NODES) v = *(const float4*)&x[(size_t)(base + n) * IN_F + k];
        xs4[(n << 5) + ((k >> 2) ^ (n & 7))] = v;
    }
    __syncthreads();

    int m0 = t & 15;           // node group (stride-16 nodes)
    int f0 = (t >> 4) << 2;    // 4 features
    int sw = m0 & 7;           // swizzle key (same for m0, m0+16, m0+32, m0+48)

    float acc[4][4];
#pragma unroll
    for (int u = 0; u < 4; ++u)
#pragma unroll
        for (int j = 0; j < 4; ++j) acc[u][j] = 0.f;

    for (int k4 = 0; k4 < IN_F; k4 += 4) {
        int cb = (k4 >> 2) ^ sw;
        float4 xv[4], wv[4];
#pragma unroll
        for (int u = 0; u < 4; ++u) xv[u] = xs4[((m0 + 16 * u) << 5) + cb];
#pragma unroll
        for (int kk = 0; kk < 4; ++kk) wv[kk] = *(float4*)&w[(k4 + kk) * HID + f0];
#pragma unroll
        for (int u = 0; u < 4; ++u) {
            acc[u][0] += xv[u].x * wv[0].x + xv[u].y * wv[1].x + xv[u].z * wv[2].x + xv[u].w * wv[3].x;
            acc[u][1] += xv[u].x * wv[0].y + xv[u].y * wv[1].y + xv[u].z * wv[2].y + xv[u].w * wv[3].y;
            acc[u][2] += xv[u].x * wv[0].z + xv[u].y * wv[1].z + xv[u].z * wv[2].z + xv[u].w * wv[3].z;
            acc[u][3] += xv[u].x * wv[0].w + xv[u].y * wv[1].w + xv[u].z * wv[2].w + xv[u].w * wv[3].w;
        }
    }

#pragma unroll
    for (int u = 0; u < 4; ++u) {
        int n = base + m0 + 16 * u;
        if (n < N_NODES) {
            float dv = dinv[n];
            *(float4*)&g1[(size_t)n * HID + f0] =
                make_float4(acc[u][0] * dv, acc[u][1] * dv, acc[u][2] * dv, acc[u][3] * dv);
        }
    }
}

// ---------------- layer 1 gather + finalize1 ----------------

__global__ __launch_bounds__(256) void gather1_kernel(const int* __restrict__ rowptr,
                                                      const int* __restrict__ deg,
                                                      const int* __restrict__ srt,
                                                      const float* __restrict__ g1,
                                                      const float* __restrict__ dinv,
                                                      const float* __restrict__ b1,
                                                      float* __restrict__ h) {
    int n = blockIdx.x * 4 + (threadIdx.x >> 6);
    int lane = threadIdx.x & 63;
    if (n >= N_NODES) return;
    int s = rowptr[n], e = s + deg[n];
    float a0 = 0.f, a1 = 0.f, a2 = 0.f, a3 = 0.f;
    float a4 = 0.f, a5 = 0.f, a6 = 0.f, a7 = 0.f;
    int j = s;
    for (; j + 8 <= e; j += 8) {
        int r0 = srt[j],     r1 = srt[j + 1], r2 = srt[j + 2], r3 = srt[j + 3];
        int r4 = srt[j + 4], r5 = srt[j + 5], r6 = srt[j + 6], r7 = srt[j + 7];
        a0 += g1[(size_t)r0 * HID + lane];
        a1 += g1[(size_t)r1 * HID + lane];
        a2 += g1[(size_t)r2 * HID + lane];
        a3 += g1[(size_t)r3 * HID + lane];
        a4 += g1[(size_t)r4 * HID + lane];
        a5 += g1[(size_t)r5 * HID + lane];
        a6 += g1[(size_t)r6 * HID + lane];
        a7 += g1[(size_t)r7 * HID + lane];
    }
    for (; j < e; ++j) a0 += g1[(size_t)srt[j] * HID + lane];
    float sum = ((a0 + a1) + (a2 + a3)) + ((a4 + a5) + (a6 + a7))
              + g1[(size_t)n * HID + lane];  // + self-loop
    float t = dinv[n] * sum + b1[lane];
    h[(size_t)n * HID + lane] = t > 0.f ? t : 0.f;
}

// ---------------- layer 2 dense: g2 = (h @ W2) * dinv ----------------
// register-tiled: tile 128 nodes x 32 f; thread = 4 nodes (stride 32) x 4 f.

__global__ __launch_bounds__(256) void gemm2_tiled(const float* __restrict__ h,
                                                   const float* __restrict__ W2,
                                                   const float* __restrict__ dinv,
                                                   float* __restrict__ g2) {
    __shared__ float w[HID * OUT_F];      // 8 KB
    __shared__ float hs[128 * HID];       // 32 KB, swizzled
    float4* hs4 = (float4*)hs;            // row stride 16 float4

    int t = threadIdx.x;
    int base = blockIdx.x * 128;

    for (int i = t; i < HID * OUT_F; i += 256) w[i] = W2[i];

#pragma unroll
    for (int j = 0; j < 8; ++j) {         // 128 rows x 64 k = 8192 floats
        int idx = j * 1024 + t * 4;
        int n = idx >> 6;                 // 0..127
        int k = idx & 63;
        float4 v = make_float4(0.f, 0.f, 0.f, 0.f);
        if (base + n < N_NODES) v = *(const float4*)&h[(size_t)(base + n) * HID + k];
        hs4[(n << 4) + ((k >> 2) ^ (n & 7))] = v;
    }
    __syncthreads();

    int m0 = t & 31;           // node group (stride-32 nodes)
    int f0 = (t >> 5) << 2;    // 4 features
    int sw = m0 & 7;

    float acc[4][4];
#pragma unroll
    for (int u = 0; u < 4; ++u)
#pragma unroll
        for (int j = 0; j < 4; ++j) acc[u][j] = 0.f;

    for (int k4 = 0; k4 < HID; k4 += 4) {
        int cb = (k4 >> 2) ^ sw;
        float4 xv[4], wv[4];
#pragma unroll
        for (int u = 0; u < 4; ++u) xv[u] = hs4[((m0 + 32 * u) << 4) + cb];
#pragma unroll
        for (int kk = 0; kk < 4; ++kk) wv[kk] = *(float4*)&w[(k4 + kk) * OUT_F + f0];
#pragma unroll
        for (int u = 0; u < 4; ++u) {
            acc[u][0] += xv[u].x * wv[0].x + xv[u].y * wv[1].x + xv[u].z * wv[2].x + xv[u].w * wv[3].x;
            acc[u][1] += xv[u].x * wv[0].y + xv[u].y * wv[1].y + xv[u].z * wv[2].y + xv[u].w * wv[3].y;
            acc[u][2] += xv[u].x * wv[0].z + xv[u].y * wv[1].z + xv[u].z * wv[2].z + xv[u].w * wv[3].z;
            acc[u][3] += xv[u].x * wv[0].w + xv[u].y * wv[1].w + xv[u].z * wv[2].w + xv[u].w * wv[3].w;
        }
    }

#pragma unroll
    for (int u = 0; u < 4; ++u) {
        int n = base + m0 + 32 * u;
        if (n < N_NODES) {
            float dv = dinv[n];
            *(float4*)&g2[(size_t)n * OUT_F + f0] =
                make_float4(acc[u][0] * dv, acc[u][1] * dv, acc[u][2] * dv, acc[u][3] * dv);
        }
    }
}

// ---------------- layer 2 gather + finalize2 ----------------

__global__ __launch_bounds__(256) void gather2_kernel(const int* __restrict__ rowptr,
                                                      const int* __restrict__ deg,
                                                      const int* __restrict__ srt,
                                                      const float* __restrict__ g2,
                                                      const float* __restrict__ dinv,
                                                      const float* __restrict__ b2,
                                                      float* __restrict__ out) {
    int n = blockIdx.x * 8 + (threadIdx.x >> 5);
    int f = threadIdx.x & 31;
    if (n >= N_NODES) return;
    int s = rowptr[n], e = s + deg[n];
    float a0 = 0.f, a1 = 0.f, a2 = 0.f, a3 = 0.f;
    float a4 = 0.f, a5 = 0.f, a6 = 0.f, a7 = 0.f;
    int j = s;
    for (; j + 8 <= e; j += 8) {
        int r0 = srt[j],     r1 = srt[j + 1], r2 = srt[j + 2], r3 = srt[j + 3];
        int r4 = srt[j + 4], r5 = srt[j + 5], r6 = srt[j + 6], r7 = srt[j + 7];
        a0 += g2[(size_t)r0 * OUT_F + f];
        a1 += g2[(size_t)r1 * OUT_F + f];
        a2 += g2[(size_t)r2 * OUT_F + f];
        a3 += g2[(size_t)r3 * OUT_F + f];
        a4 += g2[(size_t)r4 * OUT_F + f];
        a5 += g2[(size_t)r5 * OUT_F + f];
        a6 += g2[(size_t)r6 * OUT_F + f];
        a7 += g2[(size_t)r7 * OUT_F + f];
    }
    for (; j < e; ++j) a0 += g2[(size_t)srt[j] * OUT_F + f];
    float sum = ((a0 + a1) + (a2 + a3)) + ((a4 + a5) + (a6 + a7))
              + g2[(size_t)n * OUT_F + f];  // + self-loop
    out[(size_t)n * OUT_F + f] = dinv[n] * sum + b2[f];
}

extern "C" void kernel_launch(void* const* d_in, const int* in_sizes, int n_in,
                              void* d_out, int out_size, void* d_ws, size_t ws_size,
                              hipStream_t stream) {
    const float* x   = (const float*)d_in[0];
    const int*   ei  = (const int*)d_in[1];
    const int*   row = ei;             // edge_index[0] = source
    const int*   col = ei + N_EDGES;   // edge_index[1] = target
    const float* W1  = (const float*)d_in[2];
    const float* b1  = (const float*)d_in[3];
    const float* W2  = (const float*)d_in[4];
    const float* b2  = (const float*)d_in[5];
    float* out = (float*)d_out;

    // workspace layout
    char* p = (char*)d_ws;
    float* dinv  = (float*)p; p += (size_t)N_NODES * 4;          // 0.4 MB
    float* g1    = (float*)p; p += (size_t)N_NODES * HID * 4;    // 25.6 MB
    float* h     = (float*)p; p += (size_t)N_NODES * HID * 4;    // 25.6 MB
    float* g2    = (float*)p; p += (size_t)N_NODES * OUT_F * 4;  // 12.8 MB
    int*   deg   = (int*)p;   p += (size_t)N_NODES * 4;          // 0.4 MB
    int*   rowp  = (int*)p;   p += (size_t)(N_NODES + 1) * 4;    // 0.4 MB
    int*   bsum  = (int*)p;   p += 512 * 4;
    int*   gcur  = (int*)p;   p += ((NBUCK + 63) & ~63) * 4;
    int*   srt   = (int*)p;   p += (size_t)N_EDGES * 4;          // 6.4 MB
    int2*  tmp   = (int2*)h;  // alias: tmp (12.8 MB) dead before gather1 writes h

    hipMemsetAsync(deg, 0, (size_t)N_NODES * sizeof(int), stream);

    hist_kernel  <<<(N_EDGES + 255) / 256, 256, 0, stream>>>(col, deg);
    dinv_kernel  <<<NB_SCAN, 256, 0, stream>>>(deg, dinv);
    scan1_kernel <<<NB_SCAN, 256, 0, stream>>>(deg, rowp, bsum);
    scan2_kernel <<<1, 512, 0, stream>>>(bsum);
    scan3_kernel <<<NB_SCAN, 256, 0, stream>>>(rowp, bsum);
    binit_kernel <<<(NBUCK + 63) / 64, 64, 0, stream>>>(rowp, gcur);
    binA_kernel  <<<NBLK_A, 256, 0, stream>>>(row, col, gcur, tmp);
    binB_kernel  <<<NBUCK, 512, 0, stream>>>(rowp, tmp, srt);

    gemm1_tiled  <<<(N_NODES + 63) / 64, 256, 0, stream>>>(x, W1, dinv, g1);
    gather1_kernel<<<(N_NODES + 3) / 4, 256, 0, stream>>>(rowp, deg, srt, g1, dinv, b1, h);
    gemm2_tiled  <<<(N_NODES + 127) / 128, 256, 0, stream>>>(h, W2, dinv, g2);
    gather2_kernel<<<(N_NODES + 7) / 8, 256, 0, stream>>>(rowp, deg, srt, g2, dinv, b2, out);
}